// Round 8
// baseline (258.553 us; speedup 1.0000x reference)
//
#include <hip/hip_runtime.h>
#include <stdint.h>

// Problem constants
#define Bz  4
#define Tz  2048
#define Ez  1024
#define Hz  16
#define HDz 64
#define Mz  (Bz*Tz)      // 8192 rows

typedef short bf16x8 __attribute__((ext_vector_type(8)));   // 8 bf16 in 4 VGPRs
typedef float f32x4  __attribute__((ext_vector_type(4)));
typedef unsigned short u16;

// fp32 -> bf16, round-half-up (differs from RNE only on exact ties, p~2^-16)
__device__ __forceinline__ u16 f2bf(float f) {
  return (u16)((__builtin_bit_cast(uint32_t, f) + 0x8000u) >> 16);
}
// pack two floats -> bf16x2 in one v_perm_b32: 3 VALU ops total (a -> low16, b -> high16)
__device__ __forceinline__ uint32_t pack2bf(float a, float b) {
  uint32_t ua = __builtin_bit_cast(uint32_t, a) + 0x8000u;
  uint32_t ub = __builtin_bit_cast(uint32_t, b) + 0x8000u;
  return __builtin_amdgcn_perm(ub, ua, 0x07060302u);  // [ua.hi16 | ub.hi16<<16]
}
// pack two floats -> bf16x2 in ONE instruction (RNE): D.lo=bf16(a), D.hi=bf16(b)
__device__ __forceinline__ uint32_t cvtpk2bf(float a, float b) {
  uint32_t r;
  asm("v_cvt_pk_bf16_f32 %0, %1, %2" : "=v"(r) : "v"(a), "v"(b));
  return r;
}

// raw v_exp_f32 (args are bounded; no denormal fixup needed)
#if __has_builtin(__builtin_amdgcn_exp2f)
#define EXP2(x) __builtin_amdgcn_exp2f(x)
#else
#define EXP2(x) exp2f(x)
#endif

// async global->LDS, 16B per lane; LDS dest is wave-uniform base + lane*16
__device__ __forceinline__ void gl2lds16(const u16* g, u16* l) {
  __builtin_amdgcn_global_load_lds((const __attribute__((address_space(1))) void*)g,
                                   (__attribute__((address_space(3))) void*)l, 16, 0, 0);
}

// ---------------- fused fp32 -> bf16 conversion (3 tensors, 1 launch) ----------------
__global__ void cvt_f32_bf16_3(const float* __restrict__ s0, u16* __restrict__ d0, int n0,
                               const float* __restrict__ s1, u16* __restrict__ d1, int n1,
                               const float* __restrict__ s2, u16* __restrict__ d2, int n2) {
  int j = blockIdx.x * blockDim.x + threadIdx.x;
  const float* s; u16* d;
  if (j < n0) { s = s0; d = d0; }
  else {
    j -= n0;
    if (j < n1) { s = s1; d = d1; }
    else { j -= n1; if (j >= n2) return; s = s2; d = d2; }
  }
  float4 f = ((const float4*)s)[j];
  uint2 o;
  o.x = pack2bf(f.x, f.y);
  o.y = pack2bf(f.z, f.w);
  ((uint2*)d)[j] = o;
}

// ---------------- GEMM: C[M,N] = A[M,K] * W[N,K]^T + bias ----------------
// R7: occupancy-first restructure. R3 (128^2, 4-wave, 2 blk/CU) and R4
// (256x128, 8-wave, 1 blk/CU) both ran 8 waves/CU = 2 waves/SIMD and both
// measured MfmaUtil ~25% with ALL pipes <26% busy -- latency-bound, not
// pipe-bound (MFMA needs ~310 cyc/CU/K-tile, LDS ~690, wall was ~4x that).
// This version doubles waves/SIMD to 4:
//   128x128 tile, BK=64, 512 threads = 8 waves (2M x 4N), wave tile 64x32
//   (acc[4][2] = 32 VGPR), double-buffered LDS = 64 KB -> 2 blocks/CU
//   -> 16 waves/CU. __launch_bounds__(512,4) caps VGPR at 128.
// Sync skeleton = R3-proven: ONE __syncthreads per K-tile, prefetch issued
// AFTER the barrier (vmcnt(0) drain inside the next barrier lands a full
// compute phase later; with 2 blocks/CU the drain is covered by the other
// block). No setprio/sched_barrier (null-to-negative in lockstep, m190).
// XOR-of-16B-chunk swizzle (involution, both sides) -> conflict-free
// ds_read_b128 (measured 0 conflicts in R0-R6).
// MODE 0: QKV epilogue; MODE 1: proj epilogue (fp32 out)
template<int MODE>
__global__ __launch_bounds__(512, 4) void gemm_bt(
    const u16* __restrict__ A, const u16* __restrict__ Bw,
    const float* __restrict__ bias,
    u16* __restrict__ qo, u16* __restrict__ ko, u16* __restrict__ vto,
    float* __restrict__ fo)
{
  __shared__ u16 Ab[2][128*64];   // 32 KB
  __shared__ u16 Bb[2][128*64];   // 32 KB
  const int tid  = threadIdx.x;
  const int lane = tid & 63;
  const int wid  = tid >> 6;          // 0..7
  const int quad = lane >> 4;
  const int cl   = lane & 15;
  const int wm   = wid >> 2;          // 0..1 (M)
  const int wn   = wid & 3;           // 0..3 (N)
  const int bm   = blockIdx.y * 128;
  const int bn   = blockIdx.x * 128;
  const int srow = lane >> 3;         // 0..7 row within 8-row staging chunk
  const int ssw  = lane & 7;          // linear chunk position in LDS

  f32x4 acc[4][2] = {};

  // 4 gl2lds16 per thread per K-tile: 2 for A (128 rows), 2 for B (128 rows)
  auto stage = [&](int kt, int buf) {
#pragma unroll
    for (int s = 0; s < 2; ++s) {
      const int r  = s*64 + wid*8 + srow;
      const int cc = ssw ^ (r & 7);
      gl2lds16(A + (size_t)(bm + r)*Ez + kt + cc*8, &Ab[buf][(s*64 + wid*8)*64]);
    }
#pragma unroll
    for (int s = 0; s < 2; ++s) {
      const int r  = s*64 + wid*8 + srow;
      const int cc = ssw ^ (r & 7);
      gl2lds16(Bw + (size_t)(bn + r)*Ez + kt + cc*8, &Bb[buf][(s*64 + wid*8)*64]);
    }
  };

  stage(0, 0);   // prologue: tile 0 into buffer 0

#pragma unroll 2
  for (int it = 0; it < 16; ++it) {
    const int bufc = it & 1;
    __syncthreads();                    // drains staging of tile it; buf^1 free
    if (it < 15) stage((it+1)*64, bufc^1);   // prefetch AFTER the barrier
    const u16* AB = &Ab[bufc][0];
    const u16* BB = &Bb[bufc][0];
#pragma unroll
    for (int ks = 0; ks < 2; ++ks) {
      bf16x8 af[4], bfr[2];
#pragma unroll
      for (int mi = 0; mi < 4; ++mi) {
        const int row = wm*64 + mi*16 + cl;
        const int ch  = (ks*4 + quad) ^ (row & 7);
        af[mi] = *(const bf16x8*)&AB[row*64 + ch*8];
      }
#pragma unroll
      for (int ni = 0; ni < 2; ++ni) {
        const int row = wn*32 + ni*16 + cl;
        const int ch  = (ks*4 + quad) ^ (row & 7);
        bfr[ni] = *(const bf16x8*)&BB[row*64 + ch*8];
      }
#pragma unroll
      for (int mi = 0; mi < 4; ++mi)
#pragma unroll
        for (int ni = 0; ni < 2; ++ni)
          acc[mi][ni] = __builtin_amdgcn_mfma_f32_16x16x32_bf16(af[mi], bfr[ni], acc[mi][ni], 0, 0, 0);
    }
  }

  const float qsc = 0.125f * 1.4426950408889634f;  // scale * log2(e), exp2 softmax domain
#pragma unroll
  for (int ni = 0; ni < 2; ++ni) {
    const int n   = bn + wn*32 + ni*16 + cl;
    const float bv = bias[n];
#pragma unroll
    for (int mi = 0; mi < 4; ++mi) {
      const int m0 = bm + wm*64 + mi*16 + quad*4;   // C row = quad*4 + reg
      if (MODE == 0) {
        const int which = n >> 10;        // 0=q 1=k 2=v (uniform per block: 1024%128==0)
        const int e = n & 1023;
        const int h = e >> 6, d = e & 63;
        const int b = m0 >> 11, t0 = m0 & 2047;
        if (which == 2) {
          // packed 8B store of 4 consecutive t
          uint2 pk;
          pk.x = pack2bf(acc[mi][ni][0] + bv, acc[mi][ni][1] + bv);
          pk.y = pack2bf(acc[mi][ni][2] + bv, acc[mi][ni][3] + bv);
          *(uint2*)&vto[(((size_t)(b*Hz + h))*HDz + d)*Tz + t0] = pk;
        } else {
#pragma unroll
          for (int r = 0; r < 4; ++r) {
            const int t = t0 + r;
            float val = acc[mi][ni][r] + bv;
            if (which == 0) qo[(((size_t)(b*Hz + h))*Tz + t)*HDz + d] = f2bf(val * qsc);
            else            ko[(((size_t)(b*Hz + h))*Tz + t)*HDz + d] = f2bf(val);
          }
        }
      } else {
#pragma unroll
        for (int r = 0; r < 4; ++r)
          fo[(size_t)(m0 + r)*Ez + n] = acc[mi][ni][r] + bv;
      }
    }
  }
}

// ---------------- Flash attention (S^T, no-max, 64-key staging, 32-key compute halves) ----------------
// R4-exact (best measured: 76.0 us). R5's 64q/wave halved occupancy and
// regressed; R6's zero-C + setprio-around-ST regressed (setprio starves
// co-resident waves' softmax VALU -- m190 lockstep-negative case). Reverted.
// grid = (B*H, T/128) bh-major. Block = 4 waves x 32 q-rows.
// Staging: 64-key K/V tiles, double-buffered, ONE __syncthreads per tile,
// prefetch issued after the barrier. Compute in two 32-key halves (keeps
// live score state at 16 VGPRs; R1's 64-key state spilled).
// No-max softmax (bounded scores, exp2 domain; Q pre-scaled by 0.125*log2e);
// row-sums l via ones-MFMA (C-layout, shfl-free epilogue).
// P redistribution (S^T C-layout -> PV A-fragment) in registers:
// v_cvt_pk_bf16_f32 then v_permlane32_swap + v_permlane16_swap
// (R1-R3 validated bit-exact). XOR-8 chunk swizzle on K and V (0 conflicts).
__global__ __launch_bounds__(256, 4) void attn_flash(
    const u16* __restrict__ Q, const u16* __restrict__ K,
    const u16* __restrict__ Vt, const unsigned char* __restrict__ mask,
    u16* __restrict__ ctx)
{
  __shared__ u16 Kb[2][64*64];     // 8 KB per buffer  [key][dim], XOR-8 swizzle
  __shared__ u16 Vb[2][64*64];     // 8 KB per buffer  [dim][key], XOR-8 swizzle

  const int tid  = threadIdx.x;
  const int lane = tid & 63;
  const int wid  = tid >> 6;
  const int quad = lane >> 4;
  const int cl   = lane & 15;
  const int bh   = blockIdx.x;        // b*16 + h
  const int b    = bh >> 4;
  const int qrw  = blockIdx.y * 128 + wid * 32;   // wave's 32-q-row base

  // staging lane mapping: 2 gl2lds per tensor per tile per thread, 8 rows each.
  // (row+8)&7 == row&7, so one swizzled chunk index serves both loads.
  const int srow = wid*16 + (lane >> 3);           // staging row (s=0)
  const int sch  = (lane & 7) ^ (srow & 7);        // swizzled 16B chunk (of 8)
  const u16* Kg = K  + ((size_t)bh*Tz + srow)*HDz + sch*8;   // + kt*HDz per tile
  const u16* Vg = Vt + ((size_t)bh*HDz + srow)*Tz + sch*8;   // + kt per tile
  u16* KbL[2] = { &Kb[0][(wid*16)*64], &Kb[1][(wid*16)*64] };
  u16* VbL[2] = { &Vb[0][(wid*16)*64], &Vb[1][(wid*16)*64] };

  auto stage = [&](int kt, int buf) {
    gl2lds16(Kg + (size_t)kt*HDz,           KbL[buf]);
    gl2lds16(Kg + (size_t)kt*HDz + 8*HDz,   KbL[buf] + 8*64);
    gl2lds16(Vg + kt,                       VbL[buf]);
    gl2lds16(Vg + kt + (size_t)8*Tz,        VbL[buf] + 8*64);
  };

  // mask pre-scan: 2048 bytes, 32 B/lane -> wave-uniform domask
  const unsigned char* mrow_p = mask + (size_t)b * Tz;
  bool domask;
  {
    const uint4* mp = (const uint4*)mrow_p;
    uint4 a = mp[lane*2], c = mp[lane*2 + 1];
    uint32_t any = a.x | a.y | a.z | a.w | c.x | c.y | c.z | c.w;
    domask = __any(any != 0);
  }

  // Q fragments for 2 q-sub-tiles (MFMA B-operand: lane n=cl -> qrow)
  bf16x8 aq[2][2];
#pragma unroll
  for (int qb = 0; qb < 2; ++qb) {
    const u16* Qg = Q + ((size_t)bh*Tz + qrw + qb*16 + cl)*HDz;
    aq[qb][0] = *(const bf16x8*)(Qg + quad*8);
    aq[qb][1] = *(const bf16x8*)(Qg + 32 + quad*8);
  }

  // ones B-fragment for l-accumulation MFMA (bf16 1.0 = 0x3F80)
  bf16x8 ones;
#pragma unroll
  for (int i = 0; i < 8; ++i) ones[i] = (short)0x3F80;

  f32x4 o[2][4] = {};       // [qb][db]: O rows quad*4+r, dims db*16+cl
  f32x4 lacc[2] = {};       // row-sums, C-layout rows quad*4+r

  stage(0, 0);              // prologue: tile 0 into buffer 0

#pragma unroll 2
  for (int it = 0; it < 32; ++it) {
    const int bufc = it & 1;
    __syncthreads();                  // drains this tile's staging; all waves done with buf^1
    if (it < 31) stage((it+1)*64, bufc^1);   // prefetch next tile AFTER the barrier
    const u16* KB = &Kb[bufc][0];
    const u16* VB = &Vb[bufc][0];
    const int kt = it * 64;

#pragma unroll
    for (int kv = 0; kv < 2; ++kv) {
      // S^T[key][qrow] for this 32-key half: A = K rows (lane m=cl -> key), B = Q frag
      f32x4 st[2][2] = {};
#pragma unroll
      for (int kb = 0; kb < 2; ++kb) {
        bf16x8 kf[2];
#pragma unroll
        for (int nb = 0; nb < 2; ++nb) {
          const int row = kv*32 + nb*16 + cl;          // key within tile
          const int ch  = (kb*4 + quad) ^ (row & 7);
          kf[nb] = *(const bf16x8*)&KB[row*64 + ch*8];
        }
#pragma unroll
        for (int qb = 0; qb < 2; ++qb)
#pragma unroll
          for (int nb = 0; nb < 2; ++nb)
            st[qb][nb] = __builtin_amdgcn_mfma_f32_16x16x32_bf16(kf[nb], aq[qb][kb], st[qb][nb], 0, 0, 0);
      }

      if (domask) {
#pragma unroll
        for (int nb = 0; nb < 2; ++nb) {
          uint32_t mm = *(const uint32_t*)&mrow_p[kt + kv*32 + nb*16 + quad*4];
          if (mm) {
#pragma unroll
            for (int qb = 0; qb < 2; ++qb) {
              if (mm & 0x000000ffu) st[qb][nb][0] = -INFINITY;
              if (mm & 0x0000ff00u) st[qb][nb][1] = -INFINITY;
              if (mm & 0x00ff0000u) st[qb][nb][2] = -INFINITY;
              if (mm & 0xff000000u) st[qb][nb][3] = -INFINITY;
            }
          }
        }
      }

      // P = exp2(S); in-register transpose to PV A-fragment via permlane swaps.
      // u* = nb=0 (keys kv*32 + 4q+{0..3}), v* = nb=1 (keys kv*32+16+4q+{0..3})
      bf16x8 pf[2];
#pragma unroll
      for (int qb = 0; qb < 2; ++qb) {
        uint32_t ux = cvtpk2bf(EXP2(st[qb][0][0]), EXP2(st[qb][0][1]));
        uint32_t uy = cvtpk2bf(EXP2(st[qb][0][2]), EXP2(st[qb][0][3]));
        uint32_t vx = cvtpk2bf(EXP2(st[qb][1][0]), EXP2(st[qb][1][1]));
        uint32_t vy = cvtpk2bf(EXP2(st[qb][1][2]), EXP2(st[qb][1][3]));
        asm("v_permlane32_swap_b32 %0, %1" : "+v"(ux), "+v"(vx));  // ux=[u.lo,v.lo] vx=[u.hi,v.hi]
        asm("v_permlane32_swap_b32 %0, %1" : "+v"(uy), "+v"(vy));
        asm("v_permlane16_swap_b32 %0, %1" : "+v"(ux), "+v"(vx));  // ux=keys 8q+{0,1} vx=keys 8q+{4,5}
        asm("v_permlane16_swap_b32 %0, %1" : "+v"(uy), "+v"(vy));  // uy=keys 8q+{2,3} vy=keys 8q+{6,7}
        int4 pi = { (int)ux, (int)uy, (int)vx, (int)vy };
        pf[qb] = __builtin_bit_cast(bf16x8, pi);
        lacc[qb] = __builtin_amdgcn_mfma_f32_16x16x32_bf16(pf[qb], ones, lacc[qb], 0, 0, 0);
      }

      // O += P*V for this half (K-dim = 32 keys); V-frags shared across qb
#pragma unroll
      for (int db = 0; db < 4; ++db) {
        const int row = db*16 + cl;                  // dim
        const int ch  = (kv*4 + quad) ^ (row & 7);
        bf16x8 bv = *(const bf16x8*)&VB[row*64 + ch*8];
#pragma unroll
        for (int qb = 0; qb < 2; ++qb)
          o[qb][db] = __builtin_amdgcn_mfma_f32_16x16x32_bf16(pf[qb], bv, o[qb][db], 0, 0, 0);
      }
    }
  }

  // epilogue: l already in C-layout (rows quad*4+r) — no shfls; coalesced stores
#pragma unroll
  for (int qb = 0; qb < 2; ++qb) {
#pragma unroll
    for (int r = 0; r < 4; ++r) {
      const float inv = 1.0f / lacc[qb][r];
      const int t = qrw + qb*16 + quad*4 + r;
      const size_t base = ((size_t)b*Tz + t)*Ez + (size_t)(bh & 15)*HDz;
#pragma unroll
      for (int db = 0; db < 4; ++db) {
        ctx[base + db*16 + cl] = f2bf(o[qb][db][r] * inv);
      }
    }
  }
}

// ---------------- launch ----------------
extern "C" void kernel_launch(void* const* d_in, const int* in_sizes, int n_in,
                              void* d_out, int out_size, void* d_ws, size_t ws_size,
                              hipStream_t stream) {
  (void)in_sizes; (void)n_in; (void)out_size; (void)ws_size;
  const float* x      = (const float*)d_in[0];
  const unsigned char* mask = (const unsigned char*)d_in[1];   // bool, 1B
  const float* qkv_w  = (const float*)d_in[2];
  const float* qkv_b  = (const float*)d_in[3];
  const float* proj_w = (const float*)d_in[4];
  const float* proj_b = (const float*)d_in[5];
  float* out = (float*)d_out;

  // workspace layout (bytes): total 92,274,688
  char* ws = (char*)d_ws;
  u16* xb   = (u16*)(ws + 0);          // x bf16            16 MB
  u16* wqb  = (u16*)(ws + 16777216);   // qkv_w bf16         6 MB
  u16* wpb  = (u16*)(ws + 23068672);   // proj_w bf16        2 MB
  u16* Qb   = (u16*)(ws + 25165824);   // Q [B,H,T,HD]      16 MB (pre-scaled)
  u16* Kb_  = (u16*)(ws + 41943040);   // K [B,H,T,HD]      16 MB
  u16* Vtb  = (u16*)(ws + 58720256);   // V^T [B,H,HD,T]    16 MB
  u16* ctxb = (u16*)(ws + 75497472);   // attn out [B,T,E]  16 MB

  // fused conversion: 2097152 + 786432 + 262144 = 3145728 float4 groups
  cvt_f32_bf16_3<<<12288, 256, 0, stream>>>(x, xb, 2097152,
                                            qkv_w, wqb, 786432,
                                            proj_w, wpb, 262144);

  gemm_bt<0><<<dim3(24, 64), 512, 0, stream>>>(xb, wqb, qkv_b, Qb, Kb_, Vtb, nullptr);
  attn_flash<<<dim3(64, 16), 256, 0, stream>>>(Qb, Kb_, Vtb, mask, ctxb);
  gemm_bt<1><<<dim3(8, 64), 512, 0, stream>>>(ctxb, wpb, proj_b, nullptr, nullptr, nullptr, out);
}